// Round 3
// baseline (622.611 us; speedup 1.0000x reference)
//
#include <hip/hip_runtime.h>
#include <cstdint>
#include <cstddef>

// B=4, S=2048, IN=4096, OUT=4096 -> GEMM M=8192, N=4096, K=4096.
// A [M,K] fp32 -> bf16 ws; W [N,K] int32 -> dequant bf16 ws;
// C [M,N] fp32 = A·W^T + bias.
// R3: 16x16x32 -> 32x32x16 MFMA. Same fragments-per-read (bf16x8) but 2x
// MACs per MFMA => LDS read traffic and MFMA issue count halve per FLOP.

#define BM 128
#define BN 128
#define BK 32

typedef __bf16 bf16x8 __attribute__((ext_vector_type(8)));
typedef float floatx16 __attribute__((ext_vector_type(16)));
typedef float float4v __attribute__((ext_vector_type(4)));
typedef int int4v __attribute__((ext_vector_type(4)));
typedef unsigned short ushort4v __attribute__((ext_vector_type(4)));

#define AS1 __attribute__((address_space(1)))
#define AS3 __attribute__((address_space(3)))

// Async global->LDS, 16B/lane. LDS dest = wave-uniform base + lane*16
// (m104/m108) — the XOR swizzle lives on the global source address.
__device__ __forceinline__ void load16_g2l(const void* g, void* l) {
    __builtin_amdgcn_global_load_lds((const AS1 void*)(uintptr_t)g,
                                     (AS3 void*)(uint32_t)(uintptr_t)l,
                                     16, 0, 0);
}

// fp32 -> bf16 round-to-nearest-even (bit-level)
__device__ __forceinline__ unsigned short f2bf(float f) {
    union { float f; uint32_t u; } v; v.f = f;
    uint32_t u = v.u;
    uint32_t r = (u + 0x7fffu + ((u >> 16) & 1u)) >> 16;
    return (unsigned short)r;
}

// ---------------- fused pre-pass ----------------
// blocks [0, GA): A fp32->bf16, 1024 elems/block.
// blocks [GA, GA+GW): W int32->dequant bf16; row = idx >> 12 (K=4096).
__global__ __launch_bounds__(256) void prep(
    const float* __restrict__ a_in, unsigned short* __restrict__ a_out,
    const int* __restrict__ w, const float* __restrict__ scale,
    const float* __restrict__ zp, unsigned short* __restrict__ w_out,
    int ga_blocks) {
    const int bid = blockIdx.x;
    if (bid < ga_blocks) {
        const size_t i = ((size_t)bid * 256 + threadIdx.x) * 4;
        float4v f = *(const float4v*)(a_in + i);
        ushort4v r;
        r[0] = f2bf(f[0]); r[1] = f2bf(f[1]); r[2] = f2bf(f[2]); r[3] = f2bf(f[3]);
        *(ushort4v*)(a_out + i) = r;
    } else {
        const size_t i = ((size_t)(bid - ga_blocks) * 256 + threadIdx.x) * 4;
        const int row = (int)(i >> 12);
        const float s = scale[row];
        const float z = zp[row];
        int4v wv = *(const int4v*)(w + i);
        ushort4v o;
        o[0] = f2bf(((float)wv[0] - z) * s);
        o[1] = f2bf(((float)wv[1] - z) * s);
        o[2] = f2bf(((float)wv[2] - z) * s);
        o[3] = f2bf(((float)wv[3] - z) * s);
        *(ushort4v*)(w_out + i) = o;
    }
}

// ---------------- main GEMM: bf16 B^T, 32x32x16 MFMA ----------------
// 128x128 tile, BK=32, 4 waves in 2x2; each wave owns 64x64 = 2x2 of
// 32x32x16 MFMA tiles. LDS tile = 512 chunks of 16B, XOR-swizzled:
// logical (row r, chunk c) lives at physical slot p = r*4 + (c ^ ((r>>1)&3)).
__global__ __launch_bounds__(256) void gemm_bf16_bt(
    const unsigned short* __restrict__ A,  // [M,K] bf16 bits
    const unsigned short* __restrict__ B,  // [N,K] bf16 bits (W^T layout)
    const float* __restrict__ bias,        // [N]
    float* __restrict__ C,                 // [M,N] fp32
    int M, int N, int K) {
    __shared__ unsigned short lds_a[BM * BK];  // 8 KB
    __shared__ unsigned short lds_b[BN * BK];  // 8 KB

    const int tid = threadIdx.x;
    const int lane = tid & 63;
    const int wave = tid >> 6;

    const int n0 = blockIdx.x * BN;
    const int m0 = blockIdx.y * BM;

    const int wm = (wave >> 1) * 64;
    const int wn = (wave & 1) * 64;

    floatx16 acc[2][2];
#pragma unroll
    for (int i = 0; i < 2; ++i)
#pragma unroll
        for (int j = 0; j < 2; ++j)
#pragma unroll
            for (int r = 0; r < 16; ++r) acc[i][j][r] = 0.f;

    // Staging: physical slot fl holds global (row = fl>>2,
    // chunk = (fl&3) ^ ((row>>1)&3)). Two issues/thread/matrix.
    const int fl0 = tid, fl1 = tid + 256;
    const int row0 = fl0 >> 2, row1 = fl1 >> 2;
    const int kc0 = (((fl0 & 3) ^ ((row0 >> 1) & 3)) * 8);
    const int kc1 = (((fl1 & 3) ^ ((row1 >> 1) & 3)) * 8);

    const unsigned short* ga0 = A + (size_t)(m0 + row0) * K + kc0;
    const unsigned short* ga1 = A + (size_t)(m0 + row1) * K + kc1;
    const unsigned short* gb0 = B + (size_t)(n0 + row0) * K + kc0;
    const unsigned short* gb1 = B + (size_t)(n0 + row1) * K + kc1;

    unsigned short* la0 = &lds_a[fl0 * 8];
    unsigned short* la1 = &lds_a[fl1 * 8];
    unsigned short* lb0 = &lds_b[fl0 * 8];
    unsigned short* lb1 = &lds_b[fl1 * 8];

    // 32x32x16 fragment addressing: A: m = lane&31, k = (lane>>5)*8 + j.
    // Read per (m-tile tm, k-step ks): row R = wm + tm*32 + fm,
    // chunk c = (lane>>5) + 2*ks. Physical slot = R*4 + (c ^ ((fm>>1)&3))
    // (wm, tm*32 are multiples of 32 => contribute 0 to (R>>1)&3).
    const int fm = lane & 31;
    const int fq = lane >> 5;          // 0 or 1
    const int sz = (fm >> 1) & 3;      // swizzle term

    const unsigned short* ra[2][2];
    const unsigned short* rb[2][2];
#pragma unroll
    for (int t = 0; t < 2; ++t)
#pragma unroll
        for (int ks = 0; ks < 2; ++ks) {
            const int c = (fq + 2 * ks) ^ sz;
            ra[t][ks] = &lds_a[((wm + t * 32 + fm) * 4 + c) * 8];
            rb[t][ks] = &lds_b[((wn + t * 32 + fm) * 4 + c) * 8];
        }

    for (int k0 = 0; k0 < K; k0 += BK) {
        __syncthreads();  // prior iteration's LDS reads complete
        load16_g2l(ga0 + k0, la0);
        load16_g2l(ga1 + k0, la1);
        load16_g2l(gb0 + k0, lb0);
        load16_g2l(gb1 + k0, lb1);
        __syncthreads();  // staging drained

        bf16x8 av[2][2], bv[2][2];
#pragma unroll
        for (int t = 0; t < 2; ++t)
#pragma unroll
            for (int ks = 0; ks < 2; ++ks) {
                av[t][ks] = *(const bf16x8*)ra[t][ks];
                bv[t][ks] = *(const bf16x8*)rb[t][ks];
            }
#pragma unroll
        for (int ks = 0; ks < 2; ++ks)
#pragma unroll
            for (int i = 0; i < 2; ++i)
#pragma unroll
                for (int j = 0; j < 2; ++j)
                    acc[i][j] = __builtin_amdgcn_mfma_f32_32x32x16_bf16(
                        av[i][ks], bv[j][ks], acc[i][j], 0, 0, 0);
    }

    // Epilogue. 32x32 C/D layout (m74/m101): col = lane&31,
    // row = (reg&3) + 8*(reg>>2) + 4*(lane>>5). Fused bias.
    const int fr = fq * 4;
#pragma unroll
    for (int j = 0; j < 2; ++j) {
        const int col = n0 + wn + j * 32 + fm;
        const float bvl = bias[col];
#pragma unroll
        for (int i = 0; i < 2; ++i) {
            const int rbase = m0 + wm + i * 32 + fr;
#pragma unroll
            for (int r = 0; r < 16; ++r) {
                const int row = rbase + (r & 3) + 8 * (r >> 2);
                C[(size_t)row * N + col] = acc[i][j][r] + bvl;
            }
        }
    }
}

// ---------------- fallback (ws too small): naive fp32 ----------------
__global__ __launch_bounds__(256) void fallback_naive(
    const float* __restrict__ in, const int* __restrict__ w,
    const float* __restrict__ scale, const float* __restrict__ zp,
    const float* __restrict__ bias, float* __restrict__ out,
    int M, int N, int K) {
    int idx = blockIdx.x * 256 + threadIdx.x;
    if (idx >= M * N) return;
    int m = idx / N, n = idx - m * N;
    const float s = scale[n], z = zp[n];
    const float* a = in + (size_t)m * K;
    const int* wr = w + (size_t)n * K;
    float acc = 0.f;
    for (int k = 0; k < K; ++k) acc += a[k] * ((float)wr[k] - z);
    out[idx] = acc * s + bias[n];
}

extern "C" void kernel_launch(void* const* d_in, const int* in_sizes, int n_in,
                              void* d_out, int out_size, void* d_ws, size_t ws_size,
                              hipStream_t stream) {
    constexpr int M = 4 * 2048;  // B*S
    constexpr int K = 4096;      // IN
    constexpr int N = 4096;      // OUT

    const float* input = (const float*)d_in[0];
    const int* w8 = (const int*)d_in[1];
    const float* scale = (const float*)d_in[2];
    const float* zp = (const float*)d_in[3];
    const float* bias = (const float*)d_in[4];
    float* out = (float*)d_out;

    const size_t need = ((size_t)M * K + (size_t)N * K) * sizeof(unsigned short);
    if (ws_size < need) {
        const int total = M * N;
        fallback_naive<<<(total + 255) / 256, 256, 0, stream>>>(
            input, w8, scale, zp, bias, out, M, N, K);
        return;
    }

    unsigned short* wsA = (unsigned short*)d_ws;   // M*K bf16
    unsigned short* wsW = wsA + (size_t)M * K;     // N*K bf16

    const int ga_blocks = (M * K) / 1024;          // 32768
    const int gw_blocks = (N * K) / 1024;          // 16384
    prep<<<ga_blocks + gw_blocks, 256, 0, stream>>>(
        input, wsA, w8, scale, zp, wsW, ga_blocks);

    dim3 grid(N / BN, M / BM);  // (32, 64) = 2048 blocks
    gemm_bf16_bt<<<grid, 256, 0, stream>>>(wsA, wsW, bias, out, M, N, K);
}